// Round 12
// baseline (272.404 us; speedup 1.0000x reference)
//
#include <hip/hip_runtime.h>
#include <math.h>

#define BB 16
#define H 1024
#define W 1024
#define HW (H*W)
#define NTOT (BB*HW)

typedef unsigned long long u64;

// float32 of np.exp(-0.5*(n/1)^2), n=-2..2 (correctly-rounded decimal literals)
__device__ __constant__ float GW[5] = {
    0.13533528323661270f, 0.60653065971263342f, 1.0f,
    0.60653065971263342f, 0.13533528323661270f};

// NMS neighbor offsets per direction bucket
// 0:E 1:SE 2:S 3:SW 4:W 5:NW 6:N 7:NE
__device__ __constant__ int NBDY[8] = {0, 1, 1, 1, 0, -1, -1, -1};
__device__ __constant__ int NBDX[8] = {1, 1, 0, -1, -1, -1, 0, 1};

#define CSCALE ((float)(180.0 / 3.1415926))

// =====================================================================
// K1: fused gaussian(h)+gaussian(v)+sobel+mag+bucket + per-block magmax
// Tile 128x8. LDS ~16.2 KB -> 8 blocks/CU (wave cap). Bucket by pure
// comparisons (exact outside a conservative boundary band; band falls
// back to the proven exact double-atan2 chain).
// [r0-r9 evidence: this un-fused split (64-70 us K1) beats every fused
//  K1+NMS variant (114-143 us) -- pipeline is VALU-bound, so
//  recomputing sobel over halo + scattered NMS reads costs more than
//  the 96 MB of HBM traffic fusion saves at ~25% HBM utilization.]
// =====================================================================
#define TW 128
#define TH 8
__global__ __launch_bounds__(256, 8) void k_smooth_sobel(const float* __restrict__ img,
                                                         float* __restrict__ mag,
                                                         unsigned char* __restrict__ bucket,
                                                         float* __restrict__ partial) {
#pragma clang fp contract(off)
    __shared__ float sA[14 * 136 + 16];
    __shared__ float sB[14 * 132];
    __shared__ float red[256];

    const int tid = threadIdx.x;
    const int x0 = blockIdx.x * TW;
    const int y0 = blockIdx.y * TH;
    const int b = blockIdx.z;
    const size_t base = (size_t)b * HW;

    // ---- stage A: load img tile + halo (float4, all-or-nothing per vec) ----
    for (int idx = tid; idx < 14 * 34; idx += 256) {
        int r = idx / 34, v = idx - r * 34;
        int gy = y0 - 3 + r;
        int gxv = x0 - 4 + v * 4;
        float4 val = make_float4(0.f, 0.f, 0.f, 0.f);
        if (gy >= 0 && gy < H && gxv >= 0 && gxv <= W - 4)
            val = *(const float4*)&img[base + (size_t)gy * W + gxv];
        *(float4*)&sA[r * 136 + v * 4] = val;
    }
    __syncthreads();

    // ---- stage B: horizontal gaussian, 4 cols/iter ----
    for (int idx = tid; idx < 14 * 33; idx += 256) {
        int r = idx / 33, g = idx - r * 33;
        const float* p = &sA[r * 136 + g * 4];
        float4 A0 = *(const float4*)p;
        float4 A1 = *(const float4*)(p + 4);
        float4 A2 = *(const float4*)(p + 8);
        float a_[12] = {A0.x, A0.y, A0.z, A0.w, A1.x, A1.y, A1.z, A1.w,
                        A2.x, A2.y, A2.z, A2.w};
        float o[4];
#pragma unroll
        for (int j = 0; j < 4; ++j) {
            float s = 0.0f;
#pragma unroll
            for (int k = 0; k < 5; ++k) s = s + GW[k] * a_[j + 1 + k];
            o[j] = s;
        }
        *(float4*)&sB[r * 132 + g * 4] = make_float4(o[0], o[1], o[2], o[3]);
    }
    __syncthreads();

    // ---- stage C: vertical gaussian -> sm (overlays sA), ZERO at image OOB ----
    for (int idx = tid; idx < 10 * 33; idx += 256) {
        int rr = idx / 33, g = idx - rr * 33;
        float bb[20];
#pragma unroll
        for (int k = 0; k < 5; ++k) {
            float4 t = *(const float4*)&sB[(rr + k) * 132 + g * 4];
            bb[k * 4 + 0] = t.x; bb[k * 4 + 1] = t.y;
            bb[k * 4 + 2] = t.z; bb[k * 4 + 3] = t.w;
        }
        int gy = y0 - 1 + rr;
        bool rowok = (gy >= 0 && gy < H);
        float o[4];
#pragma unroll
        for (int j = 0; j < 4; ++j) {
            float s = 0.0f;
#pragma unroll
            for (int k = 0; k < 5; ++k) s = s + GW[k] * bb[k * 4 + j];
            int gx = x0 - 1 + g * 4 + j;
            o[j] = (rowok && gx >= 0 && gx < W) ? s : 0.0f;
        }
        *(float4*)&sA[rr * 136 + g * 4] = make_float4(o[0], o[1], o[2], o[3]);
    }
    __syncthreads();

    // ---- stage D: sobel + mag + bucket (comparisons), 4 px/thread ----
    const int r = tid >> 5;            // 0..7
    const int cg = (tid & 31) * 4;     // 0..124
    const int y = y0 + r;
    const float* P0 = &sA[r * 136 + cg];
    const float* P1 = P0 + 136;
    const float* P2 = P1 + 136;
    float4 q0 = *(const float4*)P0; float2 e0 = *(const float2*)(P0 + 4);
    float4 q1 = *(const float4*)P1; float2 e1 = *(const float2*)(P1 + 4);
    float4 q2 = *(const float4*)P2; float2 e2 = *(const float2*)(P2 + 4);
    float r0[6] = {q0.x, q0.y, q0.z, q0.w, e0.x, e0.y};
    float r1[6] = {q1.x, q1.y, q1.z, q1.w, e1.x, e1.y};
    float r2[6] = {q2.x, q2.y, q2.z, q2.w, e2.x, e2.y};

    float tmax = 0.0f;
    float mg[4];
    unsigned int bk = 0;
#pragma unroll
    for (int j = 0; j < 4; ++j) {
        float a00 = r0[j], a01 = r0[j + 1], a02 = r0[j + 2];
        float a10 = r1[j],                  a12 = r1[j + 2];
        float a20 = r2[j], a21 = r2[j + 1], a22 = r2[j + 2];

        float Ix = a00;
        Ix = Ix - a02;
        Ix = Ix + 2.0f * a10;
        Ix = Ix - 2.0f * a12;
        Ix = Ix + a20;
        Ix = Ix - a22;

        float Iy = a00;
        Iy = Iy + 2.0f * a01;
        Iy = Iy + a02;
        Iy = Iy - a20;
        Iy = Iy - 2.0f * a21;
        Iy = Iy - a22;

        float t1 = Ix * Ix;
        float t2 = Iy * Iy;
        float m = sqrtf(t1 + t2);
        mg[j] = m;
        tmax = fmaxf(tmax, m);

        // octant by comparisons; conservative band -> exact double fallback
        float ax = fabsf(Ix), ay = fabsf(Iy);
        float mn = fminf(ax, ay), mx = fmaxf(ax, ay);
        float cr = mn * 0.92387953f - mx * 0.38268343f;  // r*sin(alpha-22.5deg)
        int bidx;
        if (fabsf(cr) < mx * 3e-5f) {
            float fa2 = (float)atan2((double)Iy, (double)Ix);
            float d2 = fa2 * CSCALE;
            d2 = d2 + 180.0f;
            float t2d = d2 / 45.0f;
            float rr2 = rintf(t2d);
            bidx = ((int)rr2) & 7;
        } else if (ay <= ax * 0.41421356f) {          // near-horizontal
            bidx = signbit(Ix) ? 0 : 4;
        } else if (ay >= ax * 2.41421356f) {          // near-vertical
            bidx = (Iy >= 0.0f) ? 6 : 2;
        } else {                                      // diagonal
            bidx = (Iy >= 0.0f) ? ((Ix >= 0.0f) ? 5 : 7)
                                : ((Ix >= 0.0f) ? 3 : 1);
        }
        bk |= ((unsigned int)bidx) << (8 * j);
    }
    *(float4*)&mag[base + (size_t)y * W + x0 + cg] = make_float4(mg[0], mg[1], mg[2], mg[3]);
    *(unsigned int*)&bucket[base + (size_t)y * W + x0 + cg] = bk;

    red[tid] = tmax;
    __syncthreads();
    for (int s = 128; s > 0; s >>= 1) {
        if (tid < s) red[tid] = fmaxf(red[tid], red[tid + s]);
        __syncthreads();
    }
    if (tid == 0) {
        int pb = (blockIdx.z * 128 + blockIdx.y) * 8 + blockIdx.x;  // 1024 per image
        partial[pb] = red[0];
    }
}

// ---------------- per-image max over 1024 block partials ----------------
__global__ __launch_bounds__(256) void k_redmax_img(const float* __restrict__ partial,
                                                    float* __restrict__ magmax) {
    __shared__ float red[256];
    const float* p = partial + blockIdx.x * 1024;
    float m = 0.0f;
    for (int k = threadIdx.x; k < 1024; k += 256) m = fmaxf(m, p[k]);
    red[threadIdx.x] = m;
    __syncthreads();
    for (int s = 128; s > 0; s >>= 1) {
        if (threadIdx.x < s) red[threadIdx.x] = fmaxf(red[threadIdx.x], red[threadIdx.x + s]);
        __syncthreads();
    }
    if (threadIdx.x == 0) magmax[blockIdx.x] = red[0];
}

// =====================================================================
// NMS: division-free compares on RAW mag in LDS; 4 px/lane, uchar4
// bucket loads, nibble-LDS word assembly -> Mb (tile-major bitmask).
// Exactness: monotone RN(.)/M + 1.0000005f gap + rare exact divide
// fallback under wave-uniform __any.
// =====================================================================
__global__ __launch_bounds__(256, 6) void k_nms_b(const float* __restrict__ mag,
                                                  const unsigned char* __restrict__ bucket,
                                                  const float* __restrict__ magmax,
                                                  u64* __restrict__ Mb,
                                                  float* __restrict__ partial) {
#pragma clang fp contract(off)
    __shared__ float sN[34 * 136];
    __shared__ unsigned int nib32[256];
    __shared__ float red[256];

    const int tid = threadIdx.x;
    const int x0 = blockIdx.x * 128;
    const int y0 = blockIdx.y * 32;
    const int b = blockIdx.z;
    const size_t base = (size_t)b * HW;
    const float M = magmax[b];

    for (int idx = tid; idx < 34 * 34; idx += 256) {
        int r = idx / 34, v = idx - r * 34;
        int gy = y0 - 1 + r;
        int gxv = x0 - 4 + v * 4;
        float4 val = make_float4(0.f, 0.f, 0.f, 0.f);
        if (gy >= 0 && gy < H && gxv >= 0 && gxv <= W - 4)
            val = *(const float4*)&mag[base + (size_t)gy * W + gxv];
        *(float4*)&sN[r * 136 + v * 4] = val;
    }
    __syncthreads();

    const int r = tid >> 5;             // row within 8-row slab
    const int cg = (tid & 31) * 4;
    float amax = 0.0f;

    for (int k4 = 0; k4 < 4; ++k4) {
        const int rr = k4 * 8 + r;      // 0..31
        const int y = y0 + rr;
        unsigned int bk4 = *(const unsigned int*)&bucket[base + (size_t)y * W + x0 + cg];
        float4 a4 = *(const float4*)&sN[(rr + 1) * 136 + cg + 4];
        float av[4] = {a4.x, a4.y, a4.z, a4.w};
        bool im[4];
        bool bad = false;
        float bpv[4], bnv[4];
        bool g1v[4], g2v[4], f1v[4], f2v[4];
#pragma unroll
        for (int j = 0; j < 4; ++j) {
            int c = cg + j;
            int bkt = (bk4 >> (8 * j)) & 0xff;
            int dy = NBDY[bkt], dx = NBDX[bkt];
            float a = av[j];
            float bp = sN[(rr + 1 + dy) * 136 + c + 4 + dx];
            float bn = sN[(rr + 1 - dy) * 136 + c + 4 - dx];
            bpv[j] = bp; bnv[j] = bn;
            bool g1 = a > bp, g2 = a > bn;
            bool f1 = a >= bp * 1.0000005f;
            bool f2 = a >= bn * 1.0000005f;
            g1v[j] = g1; g2v[j] = g2; f1v[j] = f1; f2v[j] = f2;
            im[j] = g1 && g2;
            bad = bad || (g1 && !f1) || (g2 && !f2);
        }
        if (__any(bad)) {
#pragma unroll
            for (int j = 0; j < 4; ++j) {
                bool b1 = g1v[j] && !f1v[j];
                bool b2 = g2v[j] && !f2v[j];
                if (b1 || b2) {
                    float qa = av[j] / M;
                    bool r1 = g1v[j], r2 = g2v[j];
                    if (b1) r1 = qa > (bpv[j] / M);
                    if (b2) r2 = qa > (bnv[j] / M);
                    im[j] = r1 && r2;
                }
            }
        }
        unsigned int nib = 0;
#pragma unroll
        for (int j = 0; j < 4; ++j) {
            if (im[j]) { nib |= 1u << j; amax = fmaxf(amax, av[j]); }
        }
        nib32[tid] = nib;
        __syncthreads();
        if (tid < 16) {
            int rw = tid >> 1, h = tid & 1;
            u64 w = 0;
#pragma unroll
            for (int j = 0; j < 16; ++j)
                w |= (u64)nib32[rw * 32 + h * 16 + j] << (4 * j);
            int yy = y0 + k4 * 8 + rw;
            int widx = ((b << 8) | ((yy >> 6) << 4) | ((x0 >> 6) + h)) * 64 + (yy & 63);
            Mb[widx] = w;
        }
        __syncthreads();
    }

    red[tid] = amax;
    __syncthreads();
    for (int s = 128; s > 0; s >>= 1) {
        if (tid < s) red[tid] = fmaxf(red[tid], red[tid + s]);
        __syncthreads();
    }
    // max(thin) over block = RN(max_surviving_a / M): RN monotone => exact
    if (tid == 0)
        partial[(blockIdx.z * 32 + blockIdx.y) * 8 + blockIdx.x] = red[0] / M;
}

// ---------------- global thin-max + per-image threshold bisection ----------------
__global__ __launch_bounds__(1024) void k_finalize_thr(const float* __restrict__ partial,
                                                       float* __restrict__ hdr,
                                                       float* __restrict__ thr) {
    __shared__ float red[1024];
    float m = 0.0f;
    for (int k = threadIdx.x; k < 4096; k += 1024) m = fmaxf(m, partial[k]);
    red[threadIdx.x] = m;
    __syncthreads();
    for (int s = 512; s > 0; s >>= 1) {
        if (threadIdx.x < s) red[threadIdx.x] = fmaxf(red[threadIdx.x], red[threadIdx.x + s]);
        __syncthreads();
    }
    if (threadIdx.x == 0) hdr[16] = red[0];
    if (threadIdx.x < 32) {
        float tm = red[0];
        int t = threadIdx.x;
        float M = hdr[t >> 1];
        float T = (t & 1) ? (tm * 0.15f) : 0.00392f;
        if (0.0f / M >= T) { thr[t] = 0.0f; return; }
        unsigned int lo = 0u, hi = 0x7f800000u;
        while (hi - lo > 1u) {
            unsigned int mid = lo + ((hi - lo) >> 1);
            if (__uint_as_float(mid) / M >= T) hi = mid; else lo = mid;
        }
        thr[t] = __uint_as_float(hi);
    }
}

// ---------------- threshold: mag + is_max bits -> Sb/Wb (no division) ----------------
__global__ __launch_bounds__(256, 8) void k_thresh_b(const float* __restrict__ mag,
                                                     const u64* __restrict__ Mb,
                                                     const float* __restrict__ hdr,
                                                     const float* __restrict__ thr,
                                                     u64* __restrict__ Sb,
                                                     u64* __restrict__ Wb) {
    __shared__ unsigned int nibS[256], nibW[256];
    const int tid = threadIdx.x;
    const int x0 = blockIdx.x * 128;
    const int y0 = blockIdx.y * 32;
    const int b = blockIdx.z;
    const size_t base = (size_t)b * HW;
    const float Alo = thr[b * 2], Ahi = thr[b * 2 + 1];
    const bool snm = (hdr[16] * 0.15f <= 0.0f);
    const int r = tid >> 5;
    const int cg = (tid & 31) * 4;
    const int hl = cg >> 6;

    for (int k4 = 0; k4 < 4; ++k4) {
        const int rr = k4 * 8 + r;
        const int y = y0 + rr;
        float4 a4 = *(const float4*)&mag[base + (size_t)y * W + x0 + cg];
        float av[4] = {a4.x, a4.y, a4.z, a4.w};
        const int widx = ((b << 8) | ((y >> 6) << 4) | ((x0 >> 6) + hl)) * 64 + (y & 63);
        u64 mw = Mb[widx];
        unsigned int ns = 0, nw = 0;
#pragma unroll
        for (int j = 0; j < 4; ++j) {
            bool im = (mw >> ((cg & 63) + j)) & 1ull;
            bool strong = snm || (im && (av[j] >= Ahi));
            bool weak = (!strong) && im && (av[j] >= Alo);
            ns |= (strong ? 1u : 0u) << j;
            nw |= (weak ? 1u : 0u) << j;
        }
        nibS[tid] = ns;
        nibW[tid] = nw;
        __syncthreads();
        if (tid < 32) {
            bool isW = (tid >= 16);
            int t = tid & 15;
            int rw = t >> 1, h = t & 1;
            const unsigned int* nb = isW ? nibW : nibS;
            u64 w = 0;
#pragma unroll
            for (int j = 0; j < 16; ++j)
                w |= (u64)nb[rw * 32 + h * 16 + j] << (4 * j);
            int yy = y0 + k4 * 8 + rw;
            int widx2 = ((b << 8) | ((yy >> 6) << 4) | ((x0 >> 6) + h)) * 64 + (yy & 63);
            if (isW) Wb[widx2] = w; else Sb[widx2] = w;
        }
        __syncthreads();
    }
}

// ---------------- 64x64 bit-matrix transpose via shfl_xor (6 levels) ----------------
// Lane r holds row r (bit c = col c). After transpose lane c holds col c
// (bit r = row r). Level-j block swap (verified on 2x2 case):
//   partner y = shfl_xor(x, j)
//   lane&j==0: x = (x & ~M) | ((y << j) & M)
//   lane&j!=0: x = (x & M) | ((y >> j) & ~M)
// with M = columns having (c & j) != 0.
__device__ __forceinline__ u64 transpose64(u64 x, int lane) {
    u64 y;
    y = __shfl_xor(x, 32, 64);
    x = (lane & 32) ? ((x & 0xFFFFFFFF00000000ull) | ((y >> 32) & 0x00000000FFFFFFFFull))
                    : ((x & 0x00000000FFFFFFFFull) | ((y << 32) & 0xFFFFFFFF00000000ull));
    y = __shfl_xor(x, 16, 64);
    x = (lane & 16) ? ((x & 0xFFFF0000FFFF0000ull) | ((y >> 16) & 0x0000FFFF0000FFFFull))
                    : ((x & 0x0000FFFF0000FFFFull) | ((y << 16) & 0xFFFF0000FFFF0000ull));
    y = __shfl_xor(x, 8, 64);
    x = (lane & 8)  ? ((x & 0xFF00FF00FF00FF00ull) | ((y >> 8)  & 0x00FF00FF00FF00FFull))
                    : ((x & 0x00FF00FF00FF00FFull) | ((y << 8)  & 0xFF00FF00FF00FF00ull));
    y = __shfl_xor(x, 4, 64);
    x = (lane & 4)  ? ((x & 0xF0F0F0F0F0F0F0F0ull) | ((y >> 4)  & 0x0F0F0F0F0F0F0F0Full))
                    : ((x & 0x0F0F0F0F0F0F0F0Full) | ((y << 4)  & 0xF0F0F0F0F0F0F0F0ull));
    y = __shfl_xor(x, 2, 64);
    x = (lane & 2)  ? ((x & 0xCCCCCCCCCCCCCCCCull) | ((y >> 2)  & 0x3333333333333333ull))
                    : ((x & 0x3333333333333333ull) | ((y << 2)  & 0xCCCCCCCCCCCCCCCCull));
    y = __shfl_xor(x, 1, 64);
    x = (lane & 1)  ? ((x & 0xAAAAAAAAAAAAAAAAull) | ((y >> 1)  & 0x5555555555555555ull))
                    : ((x & 0x5555555555555555ull) | ((y << 1)  & 0xAAAAAAAAAAAAAAAAull));
    return x;
}

// horizontal Kogge-Stone flood of x through weak runs (both directions)
__device__ __forceinline__ u64 hflood(u64 x, u64 Wk) {
    x |= (x << 1) & Wk;
    x |= (x >> 1) & Wk;
    u64 pL = Wk & (Wk << 1);
    u64 pR = Wk & (Wk >> 1);
    x |= (x << 2) & pL;   x |= (x >> 2) & pR;
    pL &= pL << 2;        pR &= pR >> 2;
    x |= (x << 4) & pL;   x |= (x >> 4) & pR;
    pL &= pL << 4;        pR &= pR >> 4;
    x |= (x << 8) & pL;   x |= (x >> 8) & pR;
    pL &= pL << 8;        pR &= pR >> 8;
    x |= (x << 16) & pL;  x |= (x >> 16) & pR;
    pL &= pL << 16;       pR &= pR >> 16;
    x |= (x << 32) & pL;  x |= (x >> 32) & pR;
    return x;
}

// ---------------- hysteresis: bit-parallel 64x64 tile per wave ----------------
// r10 arithmetic: hysteresis is VALU-throughput-bound -- 4096 waves x ~60
// iters x ~90 u64-ops ~= 20 us/pass. H-KS alone left vertical chains at 1
// row/iter (r8: wash); serial-shfl V-KS regressed (r9). Fix: full V flood
// via 64x64 bit TRANSPOSE (6 shfl_xor + ~30 ops) -> H-flood in transposed
// space = full column flood. Per super-iteration: H-flood + one plain
// vertical+diagonal step (SUPERSET of the plain r0 operator) + transposed
// V-flood. Monotone, superset of plain step, subset of true closure =>
// in-tile fixpoint identical to the verified plain fixpoint => bit-identical
// output. Iterations collapse from ~60 to ~#bends of longest weak path.
template <bool LAST>
__global__ __launch_bounds__(256) void k_hyster_bits(const u64* __restrict__ Wb,
                                                     u64* __restrict__ Sb,
                                                     float* __restrict__ out) {
    const int lane = threadIdx.x & 63;
    const int t = blockIdx.x * 4 + (threadIdx.x >> 6);  // tile id = b*256+ty*16+tx
    const int ty = (t >> 4) & 15;
    const int tx = t & 15;
    const int idx = t * 64 + lane;

    u64 S = Sb[idx];
    const u64 Wk = Wb[idx];

    u64 hstat = 0;
    if (tx > 0)  hstat |= (Sb[(t - 1) * 64 + lane] >> 63) & 1ull;
    if (tx < 15) hstat |= (Sb[(t + 1) * 64 + lane] & 1ull) << 63;

    u64 halo = 0;
    if (lane == 0 && ty > 0) {
        const int ta = t - 16;
        u64 tc = Sb[ta * 64 + 63];
        u64 hh = (tc << 1) | tc | (tc >> 1);
        if (tx > 0)  hh |= (Sb[(ta - 1) * 64 + 63] >> 63) & 1ull;
        if (tx < 15) hh |= (Sb[(ta + 1) * 64 + 63] & 1ull) << 63;
        halo = hh;
    }
    if (lane == 63 && ty < 15) {
        const int tb = t + 16;
        u64 tc = Sb[tb * 64 + 0];
        u64 hh = (tc << 1) | tc | (tc >> 1);
        if (tx > 0)  hh |= (Sb[(tb - 1) * 64 + 0] >> 63) & 1ull;
        if (tx < 15) hh |= (Sb[(tb + 1) * 64 + 0] & 1ull) << 63;
        halo = hh;
    }

    // one-time injection of constant external sources (hstat own/up/dn + halo)
    {
        u64 eu = __shfl_up(hstat, 1, 64);
        u64 ed = __shfl_down(hstat, 1, 64);
        if (lane == 0)  eu = halo;
        if (lane == 63) ed = halo;
        S |= Wk & (hstat | eu | ed);
    }

    const u64 WkT = transpose64(Wk, lane);   // weak mask in transposed space

    for (int it = 0; it < 160; ++it) {
        // a) horizontal flood through weak runs
        u64 x = hflood(S, Wk);
        // b) one plain vertical+diagonal step (8-connectivity)
        u64 hh = x | (x << 1) | (x >> 1);
        u64 up = __shfl_up(hh, 1, 64);
        if (lane == 0) up = 0;
        u64 dn = __shfl_down(hh, 1, 64);
        if (lane == 63) dn = 0;
        x |= Wk & (up | dn);
        // c) full vertical flood: transpose -> H-flood -> transpose back
        u64 xt = transpose64(x, lane);
        xt = hflood(xt, WkT);
        x = transpose64(xt, lane);

        bool ch = (x != S);
        S = x;
        if (!__any(ch)) break;
    }

    if (!LAST) {
        Sb[idx] = S;
    } else {
        const int bimg = t >> 8;
        float* op = out + (size_t)bimg * HW + (size_t)(ty * 64) * W + tx * 64 + lane;
#pragma unroll 4
        for (int rr = 0; rr < 64; ++rr) {
            u64 wrow = __shfl(S, rr, 64);
            op[(size_t)rr * W] = ((wrow >> lane) & 1ull) ? 255.0f : 0.0f;
        }
    }
}

extern "C" void kernel_launch(void* const* d_in, const int* in_sizes, int n_in,
                              void* d_out, int out_size, void* d_ws, size_t ws_size,
                              hipStream_t stream) {
    (void)in_sizes; (void)n_in; (void)out_size; (void)ws_size;
    const float* img = (const float*)d_in[0];
    float* out = (float*)d_out;

    // workspace layout
    float* hdr = (float*)d_ws;                 // [0..15]=magmax, [16]=thinmax
    float* thr = hdr + 64;                     // 32 floats: per-image Alo/Ahi
    float* partialA = hdr + 128;               // 16384 floats (K1 blocks)
    float* partialB = partialA + 16384;        // 4096 floats (nms blocks)
    float* A = partialB + 4096;                // mag, 64 MB (16B-aligned)
    unsigned char* C = (unsigned char*)(A + (size_t)NTOT);  // bucket, 16 MB
    u64* Sb = (u64*)(C + (size_t)NTOT);        // strong bits, 2 MB
    u64* Wb = Sb + NTOT / 64;                  // weak bits, 2 MB
    u64* Mb = Wb + NTOT / 64;                  // is_max bits, 2 MB

    dim3 blk(256);
    k_smooth_sobel<<<dim3(8, 128, BB), blk, 0, stream>>>(img, A, C, partialA);
    k_redmax_img<<<dim3(BB), blk, 0, stream>>>(partialA, hdr);
    k_nms_b<<<dim3(8, 32, BB), blk, 0, stream>>>(A, C, hdr, Mb, partialB);
    k_finalize_thr<<<dim3(1), dim3(1024), 0, stream>>>(partialB, hdr, thr);
    k_thresh_b<<<dim3(8, 32, BB), blk, 0, stream>>>(A, Mb, hdr, thr, Sb, Wb);
    for (int p = 0; p < 5; ++p)
        k_hyster_bits<false><<<dim3(NTOT / (64 * 64) / 4), blk, 0, stream>>>(Wb, Sb, out);
    k_hyster_bits<true><<<dim3(NTOT / (64 * 64) / 4), blk, 0, stream>>>(Wb, Sb, out);
}

// Round 13
// 243.274 us; speedup vs baseline: 1.1197x; 1.1197x over previous
//
#include <hip/hip_runtime.h>
#include <math.h>

#define BB 16
#define H 1024
#define W 1024
#define HW (H*W)
#define NTOT (BB*HW)

typedef unsigned long long u64;

// float32 of np.exp(-0.5*(n/1)^2), n=-2..2 (correctly-rounded decimal literals)
__device__ __constant__ float GW[5] = {
    0.13533528323661270f, 0.60653065971263342f, 1.0f,
    0.60653065971263342f, 0.13533528323661270f};

// NMS neighbor offsets per direction bucket
// 0:E 1:SE 2:S 3:SW 4:W 5:NW 6:N 7:NE
__device__ __constant__ int NBDY[8] = {0, 1, 1, 1, 0, -1, -1, -1};
__device__ __constant__ int NBDX[8] = {1, 1, 0, -1, -1, -1, 0, 1};

#define CSCALE ((float)(180.0 / 3.1415926))

// =====================================================================
// K1: fused gaussian(h)+gaussian(v)+sobel+mag+bucket + per-block magmax
// Tile 128x8. Bucket packed 4 bits/px (dir 0-7): halves bucket traffic
// (r12 change). Block magmax via wave shfl-reduce (1 barrier vs 8).
// [r0-r12 evidence: this un-fused split (63-70 us K1) beats every fused
//  K1+NMS variant (114-143 us); hysteresis acceleration attempts
//  (H-KS r8 wash, V-KS r9 -27us, transpose r12 -32us) all refuted ->
//  iters*ops conserved by diagonal staircases.]
// =====================================================================
#define TW 128
#define TH 8
__global__ __launch_bounds__(256, 8) void k_smooth_sobel(const float* __restrict__ img,
                                                         float* __restrict__ mag,
                                                         unsigned char* __restrict__ bucket,
                                                         float* __restrict__ partial) {
#pragma clang fp contract(off)
    __shared__ float sA[14 * 136 + 16];
    __shared__ float sB[14 * 132];

    const int tid = threadIdx.x;
    const int x0 = blockIdx.x * TW;
    const int y0 = blockIdx.y * TH;
    const int b = blockIdx.z;
    const size_t base = (size_t)b * HW;

    // ---- stage A: load img tile + halo (float4, all-or-nothing per vec) ----
    for (int idx = tid; idx < 14 * 34; idx += 256) {
        int r = idx / 34, v = idx - r * 34;
        int gy = y0 - 3 + r;
        int gxv = x0 - 4 + v * 4;
        float4 val = make_float4(0.f, 0.f, 0.f, 0.f);
        if (gy >= 0 && gy < H && gxv >= 0 && gxv <= W - 4)
            val = *(const float4*)&img[base + (size_t)gy * W + gxv];
        *(float4*)&sA[r * 136 + v * 4] = val;
    }
    __syncthreads();

    // ---- stage B: horizontal gaussian, 4 cols/iter ----
    for (int idx = tid; idx < 14 * 33; idx += 256) {
        int r = idx / 33, g = idx - r * 33;
        const float* p = &sA[r * 136 + g * 4];
        float4 A0 = *(const float4*)p;
        float4 A1 = *(const float4*)(p + 4);
        float4 A2 = *(const float4*)(p + 8);
        float a_[12] = {A0.x, A0.y, A0.z, A0.w, A1.x, A1.y, A1.z, A1.w,
                        A2.x, A2.y, A2.z, A2.w};
        float o[4];
#pragma unroll
        for (int j = 0; j < 4; ++j) {
            float s = 0.0f;
#pragma unroll
            for (int k = 0; k < 5; ++k) s = s + GW[k] * a_[j + 1 + k];
            o[j] = s;
        }
        *(float4*)&sB[r * 132 + g * 4] = make_float4(o[0], o[1], o[2], o[3]);
    }
    __syncthreads();

    // ---- stage C: vertical gaussian -> sm (overlays sA), ZERO at image OOB ----
    for (int idx = tid; idx < 10 * 33; idx += 256) {
        int rr = idx / 33, g = idx - rr * 33;
        float bb[20];
#pragma unroll
        for (int k = 0; k < 5; ++k) {
            float4 t = *(const float4*)&sB[(rr + k) * 132 + g * 4];
            bb[k * 4 + 0] = t.x; bb[k * 4 + 1] = t.y;
            bb[k * 4 + 2] = t.z; bb[k * 4 + 3] = t.w;
        }
        int gy = y0 - 1 + rr;
        bool rowok = (gy >= 0 && gy < H);
        float o[4];
#pragma unroll
        for (int j = 0; j < 4; ++j) {
            float s = 0.0f;
#pragma unroll
            for (int k = 0; k < 5; ++k) s = s + GW[k] * bb[k * 4 + j];
            int gx = x0 - 1 + g * 4 + j;
            o[j] = (rowok && gx >= 0 && gx < W) ? s : 0.0f;
        }
        *(float4*)&sA[rr * 136 + g * 4] = make_float4(o[0], o[1], o[2], o[3]);
    }
    __syncthreads();

    // ---- stage D: sobel + mag + bucket (comparisons), 4 px/thread ----
    const int r = tid >> 5;            // 0..7
    const int cg = (tid & 31) * 4;     // 0..124
    const int y = y0 + r;
    const float* P0 = &sA[r * 136 + cg];
    const float* P1 = P0 + 136;
    const float* P2 = P1 + 136;
    float4 q0 = *(const float4*)P0; float2 e0 = *(const float2*)(P0 + 4);
    float4 q1 = *(const float4*)P1; float2 e1 = *(const float2*)(P1 + 4);
    float4 q2 = *(const float4*)P2; float2 e2 = *(const float2*)(P2 + 4);
    float r0[6] = {q0.x, q0.y, q0.z, q0.w, e0.x, e0.y};
    float r1[6] = {q1.x, q1.y, q1.z, q1.w, e1.x, e1.y};
    float r2[6] = {q2.x, q2.y, q2.z, q2.w, e2.x, e2.y};

    float tmax = 0.0f;
    float mg[4];
    unsigned int bk = 0;
#pragma unroll
    for (int j = 0; j < 4; ++j) {
        float a00 = r0[j], a01 = r0[j + 1], a02 = r0[j + 2];
        float a10 = r1[j],                  a12 = r1[j + 2];
        float a20 = r2[j], a21 = r2[j + 1], a22 = r2[j + 2];

        float Ix = a00;
        Ix = Ix - a02;
        Ix = Ix + 2.0f * a10;
        Ix = Ix - 2.0f * a12;
        Ix = Ix + a20;
        Ix = Ix - a22;

        float Iy = a00;
        Iy = Iy + 2.0f * a01;
        Iy = Iy + a02;
        Iy = Iy - a20;
        Iy = Iy - 2.0f * a21;
        Iy = Iy - a22;

        float t1 = Ix * Ix;
        float t2 = Iy * Iy;
        float m = sqrtf(t1 + t2);
        mg[j] = m;
        tmax = fmaxf(tmax, m);

        // octant by comparisons; conservative band -> exact double fallback
        float ax = fabsf(Ix), ay = fabsf(Iy);
        float mn = fminf(ax, ay), mx = fmaxf(ax, ay);
        float cr = mn * 0.92387953f - mx * 0.38268343f;  // r*sin(alpha-22.5deg)
        int bidx;
        if (fabsf(cr) < mx * 3e-5f) {
            float fa2 = (float)atan2((double)Iy, (double)Ix);
            float d2 = fa2 * CSCALE;
            d2 = d2 + 180.0f;
            float t2d = d2 / 45.0f;
            float rr2 = rintf(t2d);
            bidx = ((int)rr2) & 7;
        } else if (ay <= ax * 0.41421356f) {          // near-horizontal
            bidx = signbit(Ix) ? 0 : 4;
        } else if (ay >= ax * 2.41421356f) {          // near-vertical
            bidx = (Iy >= 0.0f) ? 6 : 2;
        } else {                                      // diagonal
            bidx = (Iy >= 0.0f) ? ((Ix >= 0.0f) ? 5 : 7)
                                : ((Ix >= 0.0f) ? 3 : 1);
        }
        bk |= ((unsigned int)bidx) << (4 * j);
    }
    *(float4*)&mag[base + (size_t)y * W + x0 + cg] = make_float4(mg[0], mg[1], mg[2], mg[3]);
    // 4-bit packed bucket: 4 px -> one ushort (pixel index /2 = byte index)
    *(unsigned short*)&bucket[(base + (size_t)y * W + x0 + cg) >> 1] = (unsigned short)bk;

    // block magmax: wave shfl-reduce, then 4-value combine in sB (free after C)
#pragma unroll
    for (int off = 32; off > 0; off >>= 1)
        tmax = fmaxf(tmax, __shfl_down(tmax, off));
    if ((tid & 63) == 0) sB[tid >> 6] = tmax;
    __syncthreads();
    if (tid == 0) {
        float tA = fmaxf(fmaxf(sB[0], sB[1]), fmaxf(sB[2], sB[3]));
        int pb = (blockIdx.z * 128 + blockIdx.y) * 8 + blockIdx.x;  // 1024 per image
        partial[pb] = tA;
    }
}

// ---------------- per-image max over 1024 block partials ----------------
__global__ __launch_bounds__(256) void k_redmax_img(const float* __restrict__ partial,
                                                    float* __restrict__ magmax) {
    __shared__ float red[256];
    const float* p = partial + blockIdx.x * 1024;
    float m = 0.0f;
    for (int k = threadIdx.x; k < 1024; k += 256) m = fmaxf(m, p[k]);
    red[threadIdx.x] = m;
    __syncthreads();
    for (int s = 128; s > 0; s >>= 1) {
        if (threadIdx.x < s) red[threadIdx.x] = fmaxf(red[threadIdx.x], red[threadIdx.x + s]);
        __syncthreads();
    }
    if (threadIdx.x == 0) magmax[blockIdx.x] = red[0];
}

// =====================================================================
// NMS: division-free compares on RAW mag in LDS; 4 px/lane, 4-bit
// packed bucket (ushort per 4 px), nibble-LDS word assembly -> Mb.
// Exactness: monotone RN(.)/M + 1.0000005f gap + rare exact divide
// fallback under wave-uniform __any.
// =====================================================================
__global__ __launch_bounds__(256, 6) void k_nms_b(const float* __restrict__ mag,
                                                  const unsigned char* __restrict__ bucket,
                                                  const float* __restrict__ magmax,
                                                  u64* __restrict__ Mb,
                                                  float* __restrict__ partial) {
#pragma clang fp contract(off)
    __shared__ float sN[34 * 136];
    __shared__ unsigned int nib32[256];

    const int tid = threadIdx.x;
    const int x0 = blockIdx.x * 128;
    const int y0 = blockIdx.y * 32;
    const int b = blockIdx.z;
    const size_t base = (size_t)b * HW;
    const float M = magmax[b];

    for (int idx = tid; idx < 34 * 34; idx += 256) {
        int r = idx / 34, v = idx - r * 34;
        int gy = y0 - 1 + r;
        int gxv = x0 - 4 + v * 4;
        float4 val = make_float4(0.f, 0.f, 0.f, 0.f);
        if (gy >= 0 && gy < H && gxv >= 0 && gxv <= W - 4)
            val = *(const float4*)&mag[base + (size_t)gy * W + gxv];
        *(float4*)&sN[r * 136 + v * 4] = val;
    }
    __syncthreads();

    const int r = tid >> 5;             // row within 8-row slab
    const int cg = (tid & 31) * 4;
    float amax = 0.0f;

    for (int k4 = 0; k4 < 4; ++k4) {
        const int rr = k4 * 8 + r;      // 0..31
        const int y = y0 + rr;
        unsigned int bk4 = *(const unsigned short*)&bucket[(base + (size_t)y * W + x0 + cg) >> 1];
        float4 a4 = *(const float4*)&sN[(rr + 1) * 136 + cg + 4];
        float av[4] = {a4.x, a4.y, a4.z, a4.w};
        bool im[4];
        bool bad = false;
        float bpv[4], bnv[4];
        bool g1v[4], g2v[4], f1v[4], f2v[4];
#pragma unroll
        for (int j = 0; j < 4; ++j) {
            int c = cg + j;
            int bkt = (bk4 >> (4 * j)) & 0x7;
            int dy = NBDY[bkt], dx = NBDX[bkt];
            float a = av[j];
            float bp = sN[(rr + 1 + dy) * 136 + c + 4 + dx];
            float bn = sN[(rr + 1 - dy) * 136 + c + 4 - dx];
            bpv[j] = bp; bnv[j] = bn;
            bool g1 = a > bp, g2 = a > bn;
            bool f1 = a >= bp * 1.0000005f;
            bool f2 = a >= bn * 1.0000005f;
            g1v[j] = g1; g2v[j] = g2; f1v[j] = f1; f2v[j] = f2;
            im[j] = g1 && g2;
            bad = bad || (g1 && !f1) || (g2 && !f2);
        }
        if (__any(bad)) {
#pragma unroll
            for (int j = 0; j < 4; ++j) {
                bool b1 = g1v[j] && !f1v[j];
                bool b2 = g2v[j] && !f2v[j];
                if (b1 || b2) {
                    float qa = av[j] / M;
                    bool r1 = g1v[j], r2 = g2v[j];
                    if (b1) r1 = qa > (bpv[j] / M);
                    if (b2) r2 = qa > (bnv[j] / M);
                    im[j] = r1 && r2;
                }
            }
        }
        unsigned int nib = 0;
#pragma unroll
        for (int j = 0; j < 4; ++j) {
            if (im[j]) { nib |= 1u << j; amax = fmaxf(amax, av[j]); }
        }
        nib32[tid] = nib;
        __syncthreads();
        if (tid < 16) {
            int rw = tid >> 1, h = tid & 1;
            u64 w = 0;
#pragma unroll
            for (int j = 0; j < 16; ++j)
                w |= (u64)nib32[rw * 32 + h * 16 + j] << (4 * j);
            int yy = y0 + k4 * 8 + rw;
            int widx = ((b << 8) | ((yy >> 6) << 4) | ((x0 >> 6) + h)) * 64 + (yy & 63);
            Mb[widx] = w;
        }
        __syncthreads();
    }

    // block thin-max: wave shfl-reduce + 4-value combine in sN (all sN reads
    // complete before the last k4 barrier above)
#pragma unroll
    for (int off = 32; off > 0; off >>= 1)
        amax = fmaxf(amax, __shfl_down(amax, off));
    if ((tid & 63) == 0) sN[tid >> 6] = amax;
    __syncthreads();
    // max(thin) over block = RN(max_surviving_a / M): RN monotone => exact
    if (tid == 0) {
        float tB = fmaxf(fmaxf(sN[0], sN[1]), fmaxf(sN[2], sN[3]));
        partial[(blockIdx.z * 32 + blockIdx.y) * 8 + blockIdx.x] = tB / M;
    }
}

// ---------------- global thin-max + per-image threshold bisection ----------------
__global__ __launch_bounds__(1024) void k_finalize_thr(const float* __restrict__ partial,
                                                       float* __restrict__ hdr,
                                                       float* __restrict__ thr) {
    __shared__ float red[1024];
    float m = 0.0f;
    for (int k = threadIdx.x; k < 4096; k += 1024) m = fmaxf(m, partial[k]);
    red[threadIdx.x] = m;
    __syncthreads();
    for (int s = 512; s > 0; s >>= 1) {
        if (threadIdx.x < s) red[threadIdx.x] = fmaxf(red[threadIdx.x], red[threadIdx.x + s]);
        __syncthreads();
    }
    if (threadIdx.x == 0) hdr[16] = red[0];
    if (threadIdx.x < 32) {
        float tm = red[0];
        int t = threadIdx.x;
        float M = hdr[t >> 1];
        float T = (t & 1) ? (tm * 0.15f) : 0.00392f;
        if (0.0f / M >= T) { thr[t] = 0.0f; return; }
        unsigned int lo = 0u, hi = 0x7f800000u;
        while (hi - lo > 1u) {
            unsigned int mid = lo + ((hi - lo) >> 1);
            if (__uint_as_float(mid) / M >= T) hi = mid; else lo = mid;
        }
        thr[t] = __uint_as_float(hi);
    }
}

// ---------------- threshold: mag + is_max bits -> Sb/Wb (no division) ----------------
__global__ __launch_bounds__(256, 8) void k_thresh_b(const float* __restrict__ mag,
                                                     const u64* __restrict__ Mb,
                                                     const float* __restrict__ hdr,
                                                     const float* __restrict__ thr,
                                                     u64* __restrict__ Sb,
                                                     u64* __restrict__ Wb) {
    __shared__ unsigned int nibS[256], nibW[256];
    const int tid = threadIdx.x;
    const int x0 = blockIdx.x * 128;
    const int y0 = blockIdx.y * 32;
    const int b = blockIdx.z;
    const size_t base = (size_t)b * HW;
    const float Alo = thr[b * 2], Ahi = thr[b * 2 + 1];
    const bool snm = (hdr[16] * 0.15f <= 0.0f);
    const int r = tid >> 5;
    const int cg = (tid & 31) * 4;
    const int hl = cg >> 6;

    for (int k4 = 0; k4 < 4; ++k4) {
        const int rr = k4 * 8 + r;
        const int y = y0 + rr;
        float4 a4 = *(const float4*)&mag[base + (size_t)y * W + x0 + cg];
        float av[4] = {a4.x, a4.y, a4.z, a4.w};
        const int widx = ((b << 8) | ((y >> 6) << 4) | ((x0 >> 6) + hl)) * 64 + (y & 63);
        u64 mw = Mb[widx];
        unsigned int ns = 0, nw = 0;
#pragma unroll
        for (int j = 0; j < 4; ++j) {
            bool im = (mw >> ((cg & 63) + j)) & 1ull;
            bool strong = snm || (im && (av[j] >= Ahi));
            bool weak = (!strong) && im && (av[j] >= Alo);
            ns |= (strong ? 1u : 0u) << j;
            nw |= (weak ? 1u : 0u) << j;
        }
        nibS[tid] = ns;
        nibW[tid] = nw;
        __syncthreads();
        if (tid < 32) {
            bool isW = (tid >= 16);
            int t = tid & 15;
            int rw = t >> 1, h = t & 1;
            const unsigned int* nb = isW ? nibW : nibS;
            u64 w = 0;
#pragma unroll
            for (int j = 0; j < 16; ++j)
                w |= (u64)nb[rw * 32 + h * 16 + j] << (4 * j);
            int yy = y0 + k4 * 8 + rw;
            int widx2 = ((b << 8) | ((yy >> 6) << 4) | ((x0 >> 6) + h)) * 64 + (yy & 63);
            if (isW) Wb[widx2] = w; else Sb[widx2] = w;
        }
        __syncthreads();
    }
}

// ---------------- hysteresis: bit-parallel 64x64 tile per wave, tile-major ----------------
// H-KS variant (verified exact r8/r10). Per iteration: horizontal
// Kogge-Stone flood through weak runs + one vertical step. Monotone,
// superset of one plain iteration, subset of true closure => per-pass
// fixpoint identical to the verified plain fixpoint => bit-identical.
// Constant cross-tile terms (hstat/halo) injected once before the loop.
// [r9: serial-shfl V-KS -27us; r12: transpose full-V-flood -32us --
//  convergence is diagonal-staircase-bound, do not re-add either.]
template <bool LAST>
__global__ __launch_bounds__(256) void k_hyster_bits(const u64* __restrict__ Wb,
                                                     u64* __restrict__ Sb,
                                                     float* __restrict__ out) {
    const int lane = threadIdx.x & 63;
    const int t = blockIdx.x * 4 + (threadIdx.x >> 6);  // tile id = b*256+ty*16+tx
    const int ty = (t >> 4) & 15;
    const int tx = t & 15;
    const int idx = t * 64 + lane;

    u64 S = Sb[idx];
    const u64 Wk = Wb[idx];

    u64 hstat = 0;
    if (tx > 0)  hstat |= (Sb[(t - 1) * 64 + lane] >> 63) & 1ull;
    if (tx < 15) hstat |= (Sb[(t + 1) * 64 + lane] & 1ull) << 63;

    u64 halo = 0;
    if (lane == 0 && ty > 0) {
        const int ta = t - 16;
        u64 tc = Sb[ta * 64 + 63];
        u64 hh = (tc << 1) | tc | (tc >> 1);
        if (tx > 0)  hh |= (Sb[(ta - 1) * 64 + 63] >> 63) & 1ull;
        if (tx < 15) hh |= (Sb[(ta + 1) * 64 + 63] & 1ull) << 63;
        halo = hh;
    }
    if (lane == 63 && ty < 15) {
        const int tb = t + 16;
        u64 tc = Sb[tb * 64 + 0];
        u64 hh = (tc << 1) | tc | (tc >> 1);
        if (tx > 0)  hh |= (Sb[(tb - 1) * 64 + 0] >> 63) & 1ull;
        if (tx < 15) hh |= (Sb[(tb + 1) * 64 + 0] & 1ull) << 63;
        halo = hh;
    }

    // one-time injection of constant external sources (hstat own/up/dn + halo)
    {
        u64 eu = __shfl_up(hstat, 1, 64);
        u64 ed = __shfl_down(hstat, 1, 64);
        if (lane == 0)  eu = halo;
        if (lane == 63) ed = halo;
        S |= Wk & (hstat | eu | ed);
    }

    for (int it = 0; it < 160; ++it) {
        // horizontal flood of S through weak runs (Kogge-Stone, both dirs)
        u64 x = S;
        x |= (x << 1) & Wk;
        x |= (x >> 1) & Wk;
        u64 pL = Wk & (Wk << 1);
        u64 pR = Wk & (Wk >> 1);
        x |= (x << 2) & pL;   x |= (x >> 2) & pR;
        pL &= pL << 2;        pR &= pR >> 2;
        x |= (x << 4) & pL;   x |= (x >> 4) & pR;
        pL &= pL << 4;        pR &= pR >> 4;
        x |= (x << 8) & pL;   x |= (x >> 8) & pR;
        pL &= pL << 8;        pR &= pR >> 8;
        x |= (x << 16) & pL;  x |= (x >> 16) & pR;
        pL &= pL << 16;       pR &= pR >> 16;
        x |= (x << 32) & pL;  x |= (x >> 32) & pR;
        // vertical single step (hh includes +-1 spill for diagonal adjacency)
        u64 hh = x | (x << 1) | (x >> 1);
        u64 up = __shfl_up(hh, 1, 64);
        if (lane == 0) up = 0;
        u64 dn = __shfl_down(hh, 1, 64);
        if (lane == 63) dn = 0;
        u64 nS = x | (Wk & (up | dn));
        bool ch = (nS != S);
        S = nS;
        if (!__any(ch)) break;
    }

    if (!LAST) {
        Sb[idx] = S;
    } else {
        const int bimg = t >> 8;
        float* op = out + (size_t)bimg * HW + (size_t)(ty * 64) * W + tx * 64 + lane;
#pragma unroll 4
        for (int rr = 0; rr < 64; ++rr) {
            u64 wrow = __shfl(S, rr, 64);
            op[(size_t)rr * W] = ((wrow >> lane) & 1ull) ? 255.0f : 0.0f;
        }
    }
}

extern "C" void kernel_launch(void* const* d_in, const int* in_sizes, int n_in,
                              void* d_out, int out_size, void* d_ws, size_t ws_size,
                              hipStream_t stream) {
    (void)in_sizes; (void)n_in; (void)out_size; (void)ws_size;
    const float* img = (const float*)d_in[0];
    float* out = (float*)d_out;

    // workspace layout
    float* hdr = (float*)d_ws;                 // [0..15]=magmax, [16]=thinmax
    float* thr = hdr + 64;                     // 32 floats: per-image Alo/Ahi
    float* partialA = hdr + 128;               // 16384 floats (K1 blocks)
    float* partialB = partialA + 16384;        // 4096 floats (nms blocks)
    float* A = partialB + 4096;                // mag, 64 MB (16B-aligned)
    unsigned char* C = (unsigned char*)(A + (size_t)NTOT);  // bucket (4-bit), 8 MB used
    u64* Sb = (u64*)(C + (size_t)NTOT);        // strong bits, 2 MB
    u64* Wb = Sb + NTOT / 64;                  // weak bits, 2 MB
    u64* Mb = Wb + NTOT / 64;                  // is_max bits, 2 MB

    dim3 blk(256);
    k_smooth_sobel<<<dim3(8, 128, BB), blk, 0, stream>>>(img, A, C, partialA);
    k_redmax_img<<<dim3(BB), blk, 0, stream>>>(partialA, hdr);
    k_nms_b<<<dim3(8, 32, BB), blk, 0, stream>>>(A, C, hdr, Mb, partialB);
    k_finalize_thr<<<dim3(1), dim3(1024), 0, stream>>>(partialB, hdr, thr);
    k_thresh_b<<<dim3(8, 32, BB), blk, 0, stream>>>(A, Mb, hdr, thr, Sb, Wb);
    for (int p = 0; p < 5; ++p)
        k_hyster_bits<false><<<dim3(NTOT / (64 * 64) / 4), blk, 0, stream>>>(Wb, Sb, out);
    k_hyster_bits<true><<<dim3(NTOT / (64 * 64) / 4), blk, 0, stream>>>(Wb, Sb, out);
}